// Round 2
// baseline (674.752 us; speedup 1.0000x reference)
//
#include <hip/hip_runtime.h>
#include <hip/hip_bf16.h>

typedef _Float16 h16;
typedef _Float16 h16x8 __attribute__((ext_vector_type(8)));
typedef float f32x4 __attribute__((ext_vector_type(4)));

#define DEVI static __device__ __forceinline__

constexpr int NN = 2048;     // sequence length
constexpr int DIM = 512;
constexpr int NH = 8;
constexpr int DH = 64;
constexpr int BH = 16;       // B * H
constexpr float FSCALE = 0.125f;  // DH^-0.5

DEVI f32x4 mfma16(h16x8 a, h16x8 b, f32x4 c) {
  return __builtin_amdgcn_mfma_f32_16x16x32_f16(a, b, c, 0, 0, 0);
}

DEVI void glds16(const void* g, void* l) {
  __builtin_amdgcn_global_load_lds(
      (const __attribute__((address_space(1))) unsigned int*)g,
      (__attribute__((address_space(3))) unsigned int*)l, 16, 0, 0);
}

DEVI void tri_decode(int p, int& a, int& b) {
  a = (int)((sqrtf(8.f * p + 1.f) - 1.f) * 0.5f);
  while ((a + 1) * (a + 2) / 2 <= p) ++a;
  while (a * (a + 1) / 2 > p) --a;
  b = p - a * (a + 1) / 2;
}

// ---------------- pack kernels ----------------

__global__ __launch_bounds__(256) void k_pack_x(const float* __restrict__ x, h16* __restrict__ xh) {
  int i = (blockIdx.x * 256 + threadIdx.x) * 4;
  float4 v = *(const float4*)(x + i);
  union { h16 h[4]; uint2 u; } pk;
  pk.h[0] = (h16)v.x; pk.h[1] = (h16)v.y; pk.h[2] = (h16)v.z; pk.h[3] = (h16)v.w;
  *(uint2*)(xh + i) = pk.u;
}

struct WPtrs { const float* w[7]; };

// transpose+cast each 512x512 weight: wt[o][k] = W[k][o]
__global__ __launch_bounds__(256) void k_pack_w(WPtrs wp, h16* __restrict__ wt) {
  const float* W = wp.w[blockIdx.z];
  h16* out = wt + (size_t)blockIdx.z * DIM * DIM;
  __shared__ h16 t[64][65];
  int k0 = blockIdx.x * 64, o0 = blockIdx.y * 64;
  int c = threadIdx.x & 63, r4 = threadIdx.x >> 6;
#pragma unroll
  for (int rr = 0; rr < 64; rr += 4) {
    int r = rr + r4;
    t[r][c] = (h16)W[(size_t)(k0 + r) * DIM + o0 + c];
  }
  __syncthreads();
#pragma unroll
  for (int rr = 0; rr < 64; rr += 4) {
    int r = rr + r4;
    out[(size_t)(o0 + r) * DIM + k0 + c] = t[c][r];
  }
}

// ---------------- projections ----------------
// qkv layout: [widx][bh][n][DH], widx: 0=Qu*s 1=Ku 2=Vu 3=Qc*s 4=Kc 5=Vc
__global__ __launch_bounds__(256) void k_proj(const h16* __restrict__ xh, const h16* __restrict__ wt,
                                              h16* __restrict__ qkv, h16* __restrict__ vcT) {
  int widx = blockIdx.z;
  const h16* W = wt + (size_t)widx * DIM * DIM;  // [o][k]
  int m0 = blockIdx.x * 64, o0 = blockIdx.y * 64;
  int lane = threadIdx.x & 63, wv = threadIdx.x >> 6;
  int kb = 8 * (lane >> 4);
  f32x4 acc[4] = {};
  const h16* ap = xh + (size_t)(m0 + 16 * wv + (lane & 15)) * DIM + kb;
  const h16* bp = W + (size_t)(o0 + (lane & 15)) * DIM + kb;
  for (int k0 = 0; k0 < DIM; k0 += 32) {
    h16x8 af = *(const h16x8*)(ap + k0);
#pragma unroll
    for (int t = 0; t < 4; t++) {
      h16x8 bfv = *(const h16x8*)(bp + (size_t)(16 * t) * DIM + k0);
      acc[t] = mfma16(af, bfv, acc[t]);
    }
  }
  float scl = (widx == 0 || widx == 3) ? FSCALE : 1.0f;
  // stage 64x64 tile in LDS, then coalesced vector writes
  __shared__ h16 tl[64][72];
  int rl = 16 * wv + (lane >> 4) * 4;
  int c0 = lane & 15;
#pragma unroll
  for (int t = 0; t < 4; t++)
#pragma unroll
    for (int r = 0; r < 4; r++) tl[rl + r][c0 + 16 * t] = (h16)(acc[t][r] * scl);
  __syncthreads();
  int t = threadIdx.x;
  {
    int r = t >> 2, cg = (t & 3) * 16;
    int gi = m0 + r;
    int b = gi >> 11, n = gi & 2047, h = o0 >> 6;
    h16* dst = qkv + (((size_t)widx * BH + b * NH + h) * NN + n) * DH + cg;
    *(h16x8*)dst = *(const h16x8*)&tl[r][cg];
    *(h16x8*)(dst + 8) = *(const h16x8*)&tl[r][cg + 8];
  }
  if (widx == 5) {
    int d = t >> 2, ng = (t & 3) * 16;
    int b = m0 >> 11, nbase = m0 & 2047, h = o0 >> 6;
    h16x8 w0, w1;
#pragma unroll
    for (int e = 0; e < 8; e++) { w0[e] = tl[ng + e][d]; w1[e] = tl[ng + 8 + e][d]; }
    h16* dst = vcT + ((size_t)(b * NH + h) * DH + d) * NN + nbase + ng;
    *(h16x8*)dst = w0;
    *(h16x8*)(dst + 8) = w1;
  }
}

// ---------------- term1 & sigmoid matrices ----------------
// term[i][j] = (Qc_s[i]. Vu[j]) * [j<=i]      (SCALE folded into Qc_s)
// sig [k][j] = sigmoid(Qu_s[k] . Ku[j]) * [j>k]
__global__ __launch_bounds__(256) void k_termsig(const h16* __restrict__ qkv,
                                                 h16* __restrict__ term, h16* __restrict__ sig, int bh0) {
  int pidx = blockIdx.x;
  bool is_sig = blockIdx.y != 0;
  int lz = blockIdx.z, bh = bh0 + lz;
  int a, bq;
  tri_decode(pidx, a, bq);
  int rt = is_sig ? bq : a;  // row tile (k for sig, i for term)
  int jt = is_sig ? a : bq;  // col tile (j): term j<=i, sig j>=k
  const h16* A  = qkv + ((size_t)(is_sig ? 0 : 3) * BH + bh) * NN * DH;
  const h16* Bv = qkv + ((size_t)(is_sig ? 1 : 2) * BH + bh) * NN * DH;
  h16* out = (is_sig ? sig : term) + (size_t)lz * NN * NN;
  int lane = threadIdx.x & 63, wv = threadIdx.x >> 6;
  int wy = wv >> 1, wx = wv & 1;
  int r0 = rt * 128 + 64 * wy, c0 = jt * 128 + 64 * wx;
  int kb = 8 * (lane >> 4);
  f32x4 acc[4][4] = {};
  const h16* ap = A + (size_t)(r0 + (lane & 15)) * DH + kb;
  const h16* bp = Bv + (size_t)(c0 + (lane & 15)) * DH + kb;
#pragma unroll
  for (int ks = 0; ks < 2; ks++) {
    h16x8 af[4], bfv[4];
#pragma unroll
    for (int i = 0; i < 4; i++) af[i] = *(const h16x8*)(ap + (size_t)(16 * i) * DH + 32 * ks);
#pragma unroll
    for (int j = 0; j < 4; j++) bfv[j] = *(const h16x8*)(bp + (size_t)(16 * j) * DH + 32 * ks);
#pragma unroll
    for (int i = 0; i < 4; i++)
#pragma unroll
      for (int j = 0; j < 4; j++) acc[i][j] = mfma16(af[i], bfv[j], acc[i][j]);
  }
  __shared__ h16 Clds[128][136];
  int rbase = 16 * 0 + (lane >> 4) * 4;
#pragma unroll
  for (int i = 0; i < 4; i++)
#pragma unroll
    for (int j = 0; j < 4; j++)
#pragma unroll
      for (int r = 0; r < 4; r++) {
        int rloc = 64 * wy + 16 * i + rbase + r;
        int cloc = 64 * wx + 16 * j + (lane & 15);
        int gr = rt * 128 + rloc;
        int gj = jt * 128 + cloc;
        float v = acc[i][j][r];
        float o;
        if (!is_sig) o = (gj <= gr) ? v : 0.f;
        else         o = (gj > gr) ? 1.f / (1.f + __expf(-v)) : 0.f;
        Clds[rloc][cloc] = (h16)o;
      }
  __syncthreads();
  int t = threadIdx.x;
  int rloc = t >> 1, half = t & 1;
  h16* dst = out + (size_t)(rt * 128 + rloc) * NN + jt * 128 + 64 * half;
#pragma unroll
  for (int e = 0; e < 8; e++)
    *(h16x8*)(dst + 8 * e) = *(const h16x8*)&Clds[rloc][64 * half + 8 * e];
}

// ---------------- big triangular GEMM: scores = Qc_s.Kc^T - silu(term @ sig^T), causal mask ----------------
__global__ __launch_bounds__(256) void k_scores(const h16* __restrict__ qkv,
                                                const h16* __restrict__ term, const h16* __restrict__ sig,
                                                h16* __restrict__ scores, int bh0) {
  int pidx = blockIdx.x, lz = blockIdx.z, bh = bh0 + lz;
  int It, Kt;
  tri_decode(pidx, It, Kt);  // It >= Kt
  __shared__ char pool[128 * 136 * 2];  // reused: Alds+Blds during loop, Clds in epilogue
  h16* Alds = (h16*)pool;
  h16* Blds = (h16*)(pool + 128 * 64 * 2);
  int lane = threadIdx.x & 63, wv = threadIdx.x >> 6;
  int wy = wv >> 1, wx = wv & 1;
  const h16* Ab = term + (size_t)lz * NN * NN;
  const h16* Bb = sig + (size_t)lz * NN * NN;
  int i0 = It * 128, k0 = Kt * 128;
  f32x4 acc[4][4] = {};
  int srow = 32 * wv;
  int lr = lane >> 3, lc = 8 * (lane & 7);
  for (int js = k0; js < i0 + 128; js += 64) {
#pragma unroll
    for (int inst = 0; inst < 4; inst++) {
      int r = srow + 8 * inst;
      glds16(Ab + (size_t)(i0 + r + lr) * NN + js + lc, Alds + r * 64);
      glds16(Bb + (size_t)(k0 + r + lr) * NN + js + lc, Blds + r * 64);
    }
    __syncthreads();
#pragma unroll
    for (int ks = 0; ks < 2; ks++) {
      h16x8 af[4], bfv[4];
      int co = 32 * ks + 8 * (lane >> 4);
#pragma unroll
      for (int i = 0; i < 4; i++) af[i] = *(const h16x8*)(Alds + (64 * wy + 16 * i + (lane & 15)) * 64 + co);
#pragma unroll
      for (int j = 0; j < 4; j++) bfv[j] = *(const h16x8*)(Blds + (64 * wx + 16 * j + (lane & 15)) * 64 + co);
#pragma unroll
      for (int i = 0; i < 4; i++)
#pragma unroll
        for (int j = 0; j < 4; j++) acc[i][j] = mfma16(af[i], bfv[j], acc[i][j]);
    }
    __syncthreads();
  }
  // acc = -silu(S_u)
#pragma unroll
  for (int i = 0; i < 4; i++)
#pragma unroll
    for (int j = 0; j < 4; j++)
#pragma unroll
      for (int r = 0; r < 4; r++) {
        float xv = acc[i][j][r];
        acc[i][j][r] = -xv / (1.f + __expf(-xv));
      }
  // acc += Qc_s . Kc^T   (SCALE folded into Qc_s)
  const h16* Q  = qkv + ((size_t)3 * BH + bh) * NN * DH;
  const h16* Kc = qkv + ((size_t)4 * BH + bh) * NN * DH;
  int kb = 8 * (lane >> 4);
#pragma unroll
  for (int d2 = 0; d2 < 2; d2++) {
    h16x8 af[4], bfv[4];
#pragma unroll
    for (int i = 0; i < 4; i++)
      af[i] = *(const h16x8*)(Q + (size_t)(i0 + 64 * wy + 16 * i + (lane & 15)) * DH + 32 * d2 + kb);
#pragma unroll
    for (int j = 0; j < 4; j++)
      bfv[j] = *(const h16x8*)(Kc + (size_t)(k0 + 64 * wx + 16 * j + (lane & 15)) * DH + 32 * d2 + kb);
#pragma unroll
    for (int i = 0; i < 4; i++)
#pragma unroll
      for (int j = 0; j < 4; j++) acc[i][j] = mfma16(af[i], bfv[j], acc[i][j]);
  }
  // epilogue: stage in LDS (reuse pool), coalesced vector writes
  h16 (*Clds)[136] = (h16(*)[136])pool;
#pragma unroll
  for (int i = 0; i < 4; i++)
#pragma unroll
    for (int j = 0; j < 4; j++)
#pragma unroll
      for (int r = 0; r < 4; r++) {
        int rloc = 64 * wy + 16 * i + (lane >> 4) * 4 + r;
        int cloc = 64 * wx + 16 * j + (lane & 15);
        int gi = i0 + rloc;
        int gk = k0 + cloc;
        float v = (gk <= gi) ? acc[i][j][r] : -__builtin_inff();
        Clds[rloc][cloc] = (h16)v;
      }
  __syncthreads();
  h16* sc = scores + (size_t)lz * NN * NN;
  int t = threadIdx.x;
  int rloc = t >> 1, half = t & 1;
  h16* dst = sc + (size_t)(i0 + rloc) * NN + k0 + 64 * half;
#pragma unroll
  for (int e = 0; e < 8; e++)
    *(h16x8*)(dst + 8 * e) = *(const h16x8*)&Clds[rloc][64 * half + 8 * e];
}

// ---------------- row softmax (in place, fp16 scores -> fp16 probs) ----------------
__global__ __launch_bounds__(256) void k_softmax(h16* __restrict__ sbuf) {
  int lane = threadIdx.x & 63, wv = threadIdx.x >> 6;
  int i = blockIdx.x * 4 + wv;
  int lz = blockIdx.y;
  h16* srow = sbuf + ((size_t)lz * NN + i) * NN;
  int kend = ((i >> 7) + 1) << 7;  // 128-aligned end of written region
  float v[32];
  float m = -__builtin_inff();
#pragma unroll
  for (int it = 0; it < 4; it++) {
    int base = it * 512 + lane * 8;
    if (base < kend) {
      h16x8 raw = *(const h16x8*)(srow + base);
#pragma unroll
      for (int e = 0; e < 8; e++) {
        float xv = (float)raw[e];
        v[it * 8 + e] = xv;
        m = fmaxf(m, xv);
      }
    } else {
#pragma unroll
      for (int e = 0; e < 8; e++) v[it * 8 + e] = -__builtin_inff();
    }
  }
#pragma unroll
  for (int off = 32; off > 0; off >>= 1) m = fmaxf(m, __shfl_xor(m, off));
  float s = 0.f;
#pragma unroll
  for (int t = 0; t < 32; t++) {
    float e = __expf(v[t] - m);
    v[t] = e;
    s += e;
  }
#pragma unroll
  for (int off = 32; off > 0; off >>= 1) s += __shfl_xor(s, off);
  float inv = 1.f / s;
#pragma unroll
  for (int it = 0; it < 4; it++) {
    int base = it * 512 + lane * 8;
    if (base < kend) {
      h16x8 o;
#pragma unroll
      for (int e = 0; e < 8; e++) o[e] = (h16)(v[it * 8 + e] * inv);
      *(h16x8*)(srow + base) = o;
    }
  }
}

// ---------------- PV: attn_out = P @ Vc (64-row tiles) ----------------
__global__ __launch_bounds__(256) void k_pv(const h16* __restrict__ P, const h16* __restrict__ vcT,
                                            h16* __restrict__ attn, int bh0) {
  int It64 = blockIdx.x, lz = blockIdx.z, bh = bh0 + lz;
  int lane = threadIdx.x & 63, wv = threadIdx.x >> 6;
  const h16* Pb = P + (size_t)lz * NN * NN;
  const h16* VT = vcT + (size_t)bh * DH * NN;  // [d][n]
  int i0 = It64 * 64;
  int kend = ((It64 >> 1) + 1) << 7;  // 128-aligned end of causal row extent
  f32x4 acc[4] = {};
  int kb = 8 * (lane >> 4);
  const h16* prow = Pb + (size_t)(i0 + 16 * wv + (lane & 15)) * NN;
  for (int kk = 0; kk < kend; kk += 32) {
    h16x8 af = *(const h16x8*)(prow + kk + kb);
#pragma unroll
    for (int c = 0; c < 4; c++) {
      h16x8 bfv = *(const h16x8*)(VT + (size_t)(16 * c + (lane & 15)) * NN + kk + kb);
      acc[c] = mfma16(af, bfv, acc[c]);
    }
  }
  int hh = bh & 7, b = bh >> 3;
  int ri = i0 + 16 * wv + (lane >> 4) * 4;
  int cd0 = lane & 15;
#pragma unroll
  for (int c = 0; c < 4; c++)
#pragma unroll
    for (int r = 0; r < 4; r++) {
      int gi = ri + r, gd = cd0 + 16 * c;
      attn[((size_t)b * NN + gi) * DIM + hh * DH + gd] = (h16)acc[c][r];
    }
}

// ---------------- output projection (fp32 out) ----------------
__global__ __launch_bounds__(256) void k_outproj(const h16* __restrict__ attn, const h16* __restrict__ Wt,
                                                 float* __restrict__ out) {
  int m0 = blockIdx.x * 64, o0 = blockIdx.y * 64;
  int lane = threadIdx.x & 63, wv = threadIdx.x >> 6;
  int kb = 8 * (lane >> 4);
  f32x4 acc[4] = {};
  const h16* ap = attn + (size_t)(m0 + 16 * wv + (lane & 15)) * DIM + kb;
  const h16* bp = Wt + (size_t)(o0 + (lane & 15)) * DIM + kb;
  for (int k0 = 0; k0 < DIM; k0 += 32) {
    h16x8 af = *(const h16x8*)(ap + k0);
#pragma unroll
    for (int t = 0; t < 4; t++) {
      h16x8 bfv = *(const h16x8*)(bp + (size_t)(16 * t) * DIM + k0);
      acc[t] = mfma16(af, bfv, acc[t]);
    }
  }
  int ri = m0 + 16 * wv + (lane >> 4) * 4;
  int c0 = o0 + (lane & 15);
#pragma unroll
  for (int t = 0; t < 4; t++)
#pragma unroll
    for (int r = 0; r < 4; r++) out[(size_t)(ri + r) * DIM + c0 + 16 * t] = acc[t][r];
}

// ---------------- launch ----------------

extern "C" void kernel_launch(void* const* d_in, const int* in_sizes, int n_in,
                              void* d_out, int out_size, void* d_ws, size_t ws_size,
                              hipStream_t stream) {
  const float* x = (const float*)d_in[0];
  WPtrs wp;
  for (int i = 0; i < 7; i++) wp.w[i] = (const float*)d_in[1 + i];

  char* p = (char*)d_ws;
  auto alloc = [&](size_t bytes) {
    void* r = (void*)p;
    p += (bytes + 255) & ~(size_t)255;
    return r;
  };
  h16* xh   = (h16*)alloc((size_t)4096 * DIM * 2);            // 4 MB
  h16* wt   = (h16*)alloc((size_t)7 * DIM * DIM * 2);         // 3.5 MB
  h16* qkv  = (h16*)alloc((size_t)6 * BH * NN * DH * 2);      // 24 MB
  h16* vcT  = (h16*)alloc((size_t)BH * DH * NN * 2);          // 4 MB
  h16* attn = (h16*)alloc((size_t)4096 * DIM * 2);            // 4 MB
  size_t used = (size_t)(p - (char*)d_ws);
  size_t per_bh = (size_t)NN * NN * 2;                        // 8 MB
  size_t avail = ws_size > used ? ws_size - used : 0;
  int CH = 4;  // chunk of 4 keeps term+sig+scores (96 MB) L3-resident
  while (CH > 1 && (size_t)CH * per_bh * 3 > avail) CH >>= 1;
  h16* term   = (h16*)alloc((size_t)CH * per_bh);
  h16* sig    = (h16*)alloc((size_t)CH * per_bh);
  h16* scores = (h16*)alloc((size_t)CH * per_bh);

  k_pack_x<<<dim3(2048), dim3(256), 0, stream>>>(x, xh);
  k_pack_w<<<dim3(8, 8, 7), dim3(256), 0, stream>>>(wp, wt);
  k_proj<<<dim3(64, 8, 6), dim3(256), 0, stream>>>(xh, wt, qkv, vcT);

  for (int c0 = 0; c0 < BH; c0 += CH) {
    // no memset needed: every region later read is fully written by k_termsig/k_scores
    k_termsig<<<dim3(136, 2, CH), dim3(256), 0, stream>>>(qkv, term, sig, c0);
    k_scores<<<dim3(136, 1, CH), dim3(256), 0, stream>>>(qkv, term, sig, scores, c0);
    k_softmax<<<dim3(NN / 4, CH), dim3(256), 0, stream>>>(scores);
    k_pv<<<dim3(NN / 64, 1, CH), dim3(256), 0, stream>>>(scores, vcT, attn, c0);
  }

  k_outproj<<<dim3(64, 8), dim3(256), 0, stream>>>(attn, wt + (size_t)6 * DIM * DIM, (float*)d_out);
}

// Round 3
// 436.147 us; speedup vs baseline: 1.5471x; 1.5471x over previous
//
#include <hip/hip_runtime.h>
#include <hip/hip_bf16.h>

typedef _Float16 h16;
typedef _Float16 h16x8 __attribute__((ext_vector_type(8)));
typedef float f32x4 __attribute__((ext_vector_type(4)));

#define DEVI static __device__ __forceinline__

constexpr int NN = 2048;     // sequence length
constexpr int DIM = 512;
constexpr int NH = 8;
constexpr int DH = 64;
constexpr int BH = 16;       // B * H
constexpr float FSCALE = 0.125f;  // DH^-0.5

DEVI f32x4 mfma16(h16x8 a, h16x8 b, f32x4 c) {
  return __builtin_amdgcn_mfma_f32_16x16x32_f16(a, b, c, 0, 0, 0);
}

DEVI void glds16(const void* g, void* l) {
  __builtin_amdgcn_global_load_lds(
      (const __attribute__((address_space(1))) unsigned int*)g,
      (__attribute__((address_space(3))) unsigned int*)l, 16, 0, 0);
}

DEVI void tri_decode(int p, int& a, int& b) {
  a = (int)((sqrtf(8.f * p + 1.f) - 1.f) * 0.5f);
  while ((a + 1) * (a + 2) / 2 <= p) ++a;
  while (a * (a + 1) / 2 > p) --a;
  b = p - a * (a + 1) / 2;
}

// ---------------- pack kernels ----------------

__global__ __launch_bounds__(256) void k_pack_x(const float* __restrict__ x, h16* __restrict__ xh) {
  int i = (blockIdx.x * 256 + threadIdx.x) * 4;
  float4 v = *(const float4*)(x + i);
  union { h16 h[4]; uint2 u; } pk;
  pk.h[0] = (h16)v.x; pk.h[1] = (h16)v.y; pk.h[2] = (h16)v.z; pk.h[3] = (h16)v.w;
  *(uint2*)(xh + i) = pk.u;
}

struct WPtrs { const float* w[7]; };

// transpose+cast each 512x512 weight: wt[o][k] = W[k][o]
__global__ __launch_bounds__(256) void k_pack_w(WPtrs wp, h16* __restrict__ wt) {
  const float* W = wp.w[blockIdx.z];
  h16* out = wt + (size_t)blockIdx.z * DIM * DIM;
  __shared__ h16 t[64][65];
  int k0 = blockIdx.x * 64, o0 = blockIdx.y * 64;
  int c = threadIdx.x & 63, r4 = threadIdx.x >> 6;
#pragma unroll
  for (int rr = 0; rr < 64; rr += 4) {
    int r = rr + r4;
    t[r][c] = (h16)W[(size_t)(k0 + r) * DIM + o0 + c];
  }
  __syncthreads();
#pragma unroll
  for (int rr = 0; rr < 64; rr += 4) {
    int r = rr + r4;
    out[(size_t)(o0 + r) * DIM + k0 + c] = t[c][r];
  }
}

// ---------------- fused QKV projection ----------------
// C[4096][3072] = xh[4096][512] @ wt[0:3072][512]^T, tiled 128x128, LDS-staged.
// Epilogue scatters into qkv layout [widx][bh][n][DH] (scale folded for widx 0,3)
// and writes vcT for widx==5.
__global__ __launch_bounds__(256) void k_proj(const h16* __restrict__ xh, const h16* __restrict__ wt,
                                              h16* __restrict__ qkv, h16* __restrict__ vcT) {
  __shared__ h16 pool[128 * 136];  // Al(128x64) + Bl(128x64) during loop; Clds[128][136] epilogue
  h16* Al = pool;
  h16* Bl = pool + 128 * 64;
  int m0 = blockIdx.x * 128, o0 = blockIdx.y * 128;
  int lane = threadIdx.x & 63, wv = threadIdx.x >> 6;
  int wy = wv >> 1, wx = wv & 1;
  int srow = 32 * wv;
  int lr = lane >> 3, lc = 8 * (lane & 7);
  f32x4 acc[4][4] = {};
  for (int ks0 = 0; ks0 < DIM; ks0 += 64) {
#pragma unroll
    for (int inst = 0; inst < 4; inst++) {
      int r = srow + 8 * inst;
      glds16(xh + (size_t)(m0 + r + lr) * DIM + ks0 + lc, Al + r * 64);
      glds16(wt + (size_t)(o0 + r + lr) * DIM + ks0 + lc, Bl + r * 64);
    }
    __syncthreads();
#pragma unroll
    for (int ks = 0; ks < 2; ks++) {
      h16x8 af[4], bfv[4];
      int co = 32 * ks + 8 * (lane >> 4);
#pragma unroll
      for (int i = 0; i < 4; i++) af[i] = *(const h16x8*)(Al + (64 * wy + 16 * i + (lane & 15)) * 64 + co);
#pragma unroll
      for (int j = 0; j < 4; j++) bfv[j] = *(const h16x8*)(Bl + (64 * wx + 16 * j + (lane & 15)) * 64 + co);
#pragma unroll
      for (int i = 0; i < 4; i++)
#pragma unroll
        for (int j = 0; j < 4; j++) acc[i][j] = mfma16(af[i], bfv[j], acc[i][j]);
    }
    __syncthreads();
  }
  int widx = o0 >> 9;
  float scl = (widx == 0 || widx == 3) ? FSCALE : 1.0f;
  h16 (*Clds)[136] = (h16(*)[136])pool;
#pragma unroll
  for (int i = 0; i < 4; i++)
#pragma unroll
    for (int j = 0; j < 4; j++)
#pragma unroll
      for (int r = 0; r < 4; r++) {
        int rloc = 64 * wy + 16 * i + (lane >> 4) * 4 + r;
        int cloc = 64 * wx + 16 * j + (lane & 15);
        Clds[rloc][cloc] = (h16)(acc[i][j][r] * scl);
      }
  __syncthreads();
  int t = threadIdx.x;
  {
    int rloc = t >> 1, half = t & 1;
    int gi = m0 + rloc;
    int b = gi >> 11, n = gi & 2047;
    int og = o0 + 64 * half;
    int h = (og >> 6) & 7;
    h16* dst = qkv + (((size_t)widx * BH + b * NH + h) * NN + n) * DH;
#pragma unroll
    for (int e = 0; e < 8; e++)
      *(h16x8*)(dst + 8 * e) = *(const h16x8*)&Clds[rloc][64 * half + 8 * e];
  }
  if (widx == 5) {
    int c = t & 127, rq = t >> 7;
    int og = o0 + c;
    int h = (og >> 6) & 7, d = og & 63;
    int b = m0 >> 11, nb = (m0 & 2047) + rq * 64;
    h16* dst = vcT + ((size_t)(b * NH + h) * DH + d) * NN + nb;
#pragma unroll
    for (int g = 0; g < 8; g++) {
      h16x8 w;
#pragma unroll
      for (int e = 0; e < 8; e++) w[e] = Clds[rq * 64 + 8 * g + e][c];
      *(h16x8*)(dst + 8 * g) = w;
    }
  }
}

// ---------------- term1 & sigmoid matrices ----------------
// term[i][j] = (Qc_s[i]. Vu[j]) * [j<=i]      (SCALE folded into Qc_s)
// sig [k][j] = sigmoid(Qu_s[k] . Ku[j]) * [j>k]
__global__ __launch_bounds__(256) void k_termsig(const h16* __restrict__ qkv,
                                                 h16* __restrict__ term, h16* __restrict__ sig, int bh0) {
  int pidx = blockIdx.x;
  bool is_sig = blockIdx.y != 0;
  int lz = blockIdx.z, bh = bh0 + lz;
  int a, bq;
  tri_decode(pidx, a, bq);
  int rt = is_sig ? bq : a;  // row tile (k for sig, i for term)
  int jt = is_sig ? a : bq;  // col tile (j): term j<=i, sig j>=k
  const h16* A  = qkv + ((size_t)(is_sig ? 0 : 3) * BH + bh) * NN * DH;
  const h16* Bv = qkv + ((size_t)(is_sig ? 1 : 2) * BH + bh) * NN * DH;
  h16* out = (is_sig ? sig : term) + (size_t)lz * NN * NN;
  int lane = threadIdx.x & 63, wv = threadIdx.x >> 6;
  int wy = wv >> 1, wx = wv & 1;
  int r0 = rt * 128 + 64 * wy, c0 = jt * 128 + 64 * wx;
  int kb = 8 * (lane >> 4);
  f32x4 acc[4][4] = {};
  const h16* ap = A + (size_t)(r0 + (lane & 15)) * DH + kb;
  const h16* bp = Bv + (size_t)(c0 + (lane & 15)) * DH + kb;
#pragma unroll
  for (int ks = 0; ks < 2; ks++) {
    h16x8 af[4], bfv[4];
#pragma unroll
    for (int i = 0; i < 4; i++) af[i] = *(const h16x8*)(ap + (size_t)(16 * i) * DH + 32 * ks);
#pragma unroll
    for (int j = 0; j < 4; j++) bfv[j] = *(const h16x8*)(bp + (size_t)(16 * j) * DH + 32 * ks);
#pragma unroll
    for (int i = 0; i < 4; i++)
#pragma unroll
      for (int j = 0; j < 4; j++) acc[i][j] = mfma16(af[i], bfv[j], acc[i][j]);
  }
  __shared__ h16 Clds[128][136];
#pragma unroll
  for (int i = 0; i < 4; i++)
#pragma unroll
    for (int j = 0; j < 4; j++)
#pragma unroll
      for (int r = 0; r < 4; r++) {
        int rloc = 64 * wy + 16 * i + (lane >> 4) * 4 + r;
        int cloc = 64 * wx + 16 * j + (lane & 15);
        int gr = rt * 128 + rloc;
        int gj = jt * 128 + cloc;
        float v = acc[i][j][r];
        float o;
        if (!is_sig) o = (gj <= gr) ? v : 0.f;
        else         o = (gj > gr) ? 1.f / (1.f + __expf(-v)) : 0.f;
        Clds[rloc][cloc] = (h16)o;
      }
  __syncthreads();
  int t = threadIdx.x;
  int rloc = t >> 1, half = t & 1;
  h16* dst = out + (size_t)(rt * 128 + rloc) * NN + jt * 128 + 64 * half;
#pragma unroll
  for (int e = 0; e < 8; e++)
    *(h16x8*)(dst + 8 * e) = *(const h16x8*)&Clds[rloc][64 * half + 8 * e];
}

// ---------------- big triangular GEMM: scores = Qc_s.Kc^T - silu(term @ sig^T), causal mask ----------------
__global__ __launch_bounds__(256) void k_scores(const h16* __restrict__ qkv,
                                                const h16* __restrict__ term, const h16* __restrict__ sig,
                                                h16* __restrict__ scores, int bh0) {
  int pidx = blockIdx.x, lz = blockIdx.z, bh = bh0 + lz;
  int It, Kt;
  tri_decode(pidx, It, Kt);  // It >= Kt
  __shared__ char pool[128 * 136 * 2];  // reused: Alds+Blds during loop, Clds in epilogue
  h16* Alds = (h16*)pool;
  h16* Blds = (h16*)(pool + 128 * 64 * 2);
  int lane = threadIdx.x & 63, wv = threadIdx.x >> 6;
  int wy = wv >> 1, wx = wv & 1;
  const h16* Ab = term + (size_t)lz * NN * NN;
  const h16* Bb = sig + (size_t)lz * NN * NN;
  int i0 = It * 128, k0 = Kt * 128;
  f32x4 acc[4][4] = {};
  int srow = 32 * wv;
  int lr = lane >> 3, lc = 8 * (lane & 7);
  for (int js = k0; js < i0 + 128; js += 64) {
#pragma unroll
    for (int inst = 0; inst < 4; inst++) {
      int r = srow + 8 * inst;
      glds16(Ab + (size_t)(i0 + r + lr) * NN + js + lc, Alds + r * 64);
      glds16(Bb + (size_t)(k0 + r + lr) * NN + js + lc, Blds + r * 64);
    }
    __syncthreads();
#pragma unroll
    for (int ks = 0; ks < 2; ks++) {
      h16x8 af[4], bfv[4];
      int co = 32 * ks + 8 * (lane >> 4);
#pragma unroll
      for (int i = 0; i < 4; i++) af[i] = *(const h16x8*)(Alds + (64 * wy + 16 * i + (lane & 15)) * 64 + co);
#pragma unroll
      for (int j = 0; j < 4; j++) bfv[j] = *(const h16x8*)(Blds + (64 * wx + 16 * j + (lane & 15)) * 64 + co);
#pragma unroll
      for (int i = 0; i < 4; i++)
#pragma unroll
        for (int j = 0; j < 4; j++) acc[i][j] = mfma16(af[i], bfv[j], acc[i][j]);
    }
    __syncthreads();
  }
  // acc = -silu(S_u)
#pragma unroll
  for (int i = 0; i < 4; i++)
#pragma unroll
    for (int j = 0; j < 4; j++)
#pragma unroll
      for (int r = 0; r < 4; r++) {
        float xv = acc[i][j][r];
        acc[i][j][r] = -xv / (1.f + __expf(-xv));
      }
  // acc += Qc_s . Kc^T   (SCALE folded into Qc_s)
  const h16* Q  = qkv + ((size_t)3 * BH + bh) * NN * DH;
  const h16* Kc = qkv + ((size_t)4 * BH + bh) * NN * DH;
  int kb = 8 * (lane >> 4);
#pragma unroll
  for (int d2 = 0; d2 < 2; d2++) {
    h16x8 af[4], bfv[4];
#pragma unroll
    for (int i = 0; i < 4; i++)
      af[i] = *(const h16x8*)(Q + (size_t)(i0 + 64 * wy + 16 * i + (lane & 15)) * DH + 32 * d2 + kb);
#pragma unroll
    for (int j = 0; j < 4; j++)
      bfv[j] = *(const h16x8*)(Kc + (size_t)(k0 + 64 * wx + 16 * j + (lane & 15)) * DH + 32 * d2 + kb);
#pragma unroll
    for (int i = 0; i < 4; i++)
#pragma unroll
      for (int j = 0; j < 4; j++) acc[i][j] = mfma16(af[i], bfv[j], acc[i][j]);
  }
  // epilogue: stage in LDS (reuse pool), coalesced vector writes
  h16 (*Clds)[136] = (h16(*)[136])pool;
#pragma unroll
  for (int i = 0; i < 4; i++)
#pragma unroll
    for (int j = 0; j < 4; j++)
#pragma unroll
      for (int r = 0; r < 4; r++) {
        int rloc = 64 * wy + 16 * i + (lane >> 4) * 4 + r;
        int cloc = 64 * wx + 16 * j + (lane & 15);
        int gi = i0 + rloc;
        int gk = k0 + cloc;
        float v = (gk <= gi) ? acc[i][j][r] : -__builtin_inff();
        Clds[rloc][cloc] = (h16)v;
      }
  __syncthreads();
  h16* sc = scores + (size_t)lz * NN * NN;
  int t = threadIdx.x;
  int rloc = t >> 1, half = t & 1;
  h16* dst = sc + (size_t)(i0 + rloc) * NN + k0 + 64 * half;
#pragma unroll
  for (int e = 0; e < 8; e++)
    *(h16x8*)(dst + 8 * e) = *(const h16x8*)&Clds[rloc][64 * half + 8 * e];
}

// ---------------- row softmax (in place, fp16 scores -> fp16 probs) ----------------
__global__ __launch_bounds__(256) void k_softmax(h16* __restrict__ sbuf) {
  int lane = threadIdx.x & 63, wv = threadIdx.x >> 6;
  int i = blockIdx.x * 4 + wv;
  int lz = blockIdx.y;
  h16* srow = sbuf + ((size_t)lz * NN + i) * NN;
  int kend = ((i >> 7) + 1) << 7;  // 128-aligned end of written region
  float v[32];
  float m = -__builtin_inff();
#pragma unroll
  for (int it = 0; it < 4; it++) {
    int base = it * 512 + lane * 8;
    if (base < kend) {
      h16x8 raw = *(const h16x8*)(srow + base);
#pragma unroll
      for (int e = 0; e < 8; e++) {
        float xv = (float)raw[e];
        v[it * 8 + e] = xv;
        m = fmaxf(m, xv);
      }
    } else {
#pragma unroll
      for (int e = 0; e < 8; e++) v[it * 8 + e] = -__builtin_inff();
    }
  }
#pragma unroll
  for (int off = 32; off > 0; off >>= 1) m = fmaxf(m, __shfl_xor(m, off));
  float s = 0.f;
#pragma unroll
  for (int t = 0; t < 32; t++) {
    float e = __expf(v[t] - m);
    v[t] = e;
    s += e;
  }
#pragma unroll
  for (int off = 32; off > 0; off >>= 1) s += __shfl_xor(s, off);
  float inv = 1.f / s;
#pragma unroll
  for (int it = 0; it < 4; it++) {
    int base = it * 512 + lane * 8;
    if (base < kend) {
      h16x8 o;
#pragma unroll
      for (int e = 0; e < 8; e++) o[e] = (h16)(v[it * 8 + e] * inv);
      *(h16x8*)(srow + base) = o;
    }
  }
}

// ---------------- PV: attn_out = P @ Vc (64-row tiles) ----------------
__global__ __launch_bounds__(256) void k_pv(const h16* __restrict__ P, const h16* __restrict__ vcT,
                                            h16* __restrict__ attn, int bh0) {
  int It64 = blockIdx.x, lz = blockIdx.z, bh = bh0 + lz;
  int lane = threadIdx.x & 63, wv = threadIdx.x >> 6;
  const h16* Pb = P + (size_t)lz * NN * NN;
  const h16* VT = vcT + (size_t)bh * DH * NN;  // [d][n]
  int i0 = It64 * 64;
  int kend = ((It64 >> 1) + 1) << 7;  // 128-aligned end of causal row extent
  f32x4 acc[4] = {};
  int kb = 8 * (lane >> 4);
  const h16* prow = Pb + (size_t)(i0 + 16 * wv + (lane & 15)) * NN;
  for (int kk = 0; kk < kend; kk += 32) {
    h16x8 af = *(const h16x8*)(prow + kk + kb);
#pragma unroll
    for (int c = 0; c < 4; c++) {
      h16x8 bfv = *(const h16x8*)(VT + (size_t)(16 * c + (lane & 15)) * NN + kk + kb);
      acc[c] = mfma16(af, bfv, acc[c]);
    }
  }
  int hh = bh & 7, b = bh >> 3;
  int ri = i0 + 16 * wv + (lane >> 4) * 4;
  int cd0 = lane & 15;
#pragma unroll
  for (int c = 0; c < 4; c++)
#pragma unroll
    for (int r = 0; r < 4; r++) {
      int gi = ri + r, gd = cd0 + 16 * c;
      attn[((size_t)b * NN + gi) * DIM + hh * DH + gd] = (h16)acc[c][r];
    }
}

// ---------------- output projection (fp32 out) ----------------
__global__ __launch_bounds__(256) void k_outproj(const h16* __restrict__ attn, const h16* __restrict__ Wt,
                                                 float* __restrict__ out) {
  int m0 = blockIdx.x * 64, o0 = blockIdx.y * 64;
  int lane = threadIdx.x & 63, wv = threadIdx.x >> 6;
  int kb = 8 * (lane >> 4);
  f32x4 acc[4] = {};
  const h16* ap = attn + (size_t)(m0 + 16 * wv + (lane & 15)) * DIM + kb;
  const h16* bp = Wt + (size_t)(o0 + (lane & 15)) * DIM + kb;
  for (int k0 = 0; k0 < DIM; k0 += 32) {
    h16x8 af = *(const h16x8*)(ap + k0);
#pragma unroll
    for (int t = 0; t < 4; t++) {
      h16x8 bfv = *(const h16x8*)(bp + (size_t)(16 * t) * DIM + k0);
      acc[t] = mfma16(af, bfv, acc[t]);
    }
  }
  int ri = m0 + 16 * wv + (lane >> 4) * 4;
  int c0 = o0 + (lane & 15);
#pragma unroll
  for (int t = 0; t < 4; t++)
#pragma unroll
    for (int r = 0; r < 4; r++) out[(size_t)(ri + r) * DIM + c0 + 16 * t] = acc[t][r];
}

// ---------------- launch ----------------

extern "C" void kernel_launch(void* const* d_in, const int* in_sizes, int n_in,
                              void* d_out, int out_size, void* d_ws, size_t ws_size,
                              hipStream_t stream) {
  const float* x = (const float*)d_in[0];
  WPtrs wp;
  for (int i = 0; i < 7; i++) wp.w[i] = (const float*)d_in[1 + i];

  char* p = (char*)d_ws;
  auto alloc = [&](size_t bytes) {
    void* r = (void*)p;
    p += (bytes + 255) & ~(size_t)255;
    return r;
  };
  h16* xh   = (h16*)alloc((size_t)4096 * DIM * 2);            // 4 MB
  h16* wt   = (h16*)alloc((size_t)7 * DIM * DIM * 2);         // 3.5 MB
  h16* qkv  = (h16*)alloc((size_t)6 * BH * NN * DH * 2);      // 24 MB
  h16* vcT  = (h16*)alloc((size_t)BH * DH * NN * 2);          // 4 MB
  h16* attn = (h16*)alloc((size_t)4096 * DIM * 2);            // 4 MB
  size_t used = (size_t)(p - (char*)d_ws);
  size_t per_bh = (size_t)NN * NN * 2;                        // 8 MB
  size_t avail = ws_size > used ? ws_size - used : 0;
  int CH = 16;  // ws fits 3x128MB (round-1 evidence); fallback halves if not
  while (CH > 1 && (size_t)CH * per_bh * 3 > avail) CH >>= 1;
  h16* term   = (h16*)alloc((size_t)CH * per_bh);
  h16* sig    = (h16*)alloc((size_t)CH * per_bh);
  h16* scores = (h16*)alloc((size_t)CH * per_bh);

  k_pack_x<<<dim3(2048), dim3(256), 0, stream>>>(x, xh);
  k_pack_w<<<dim3(8, 8, 7), dim3(256), 0, stream>>>(wp, wt);
  k_proj<<<dim3(32, 24), dim3(256), 0, stream>>>(xh, wt, qkv, vcT);

  for (int c0 = 0; c0 < BH; c0 += CH) {
    // no memset needed: every region later read is fully written by k_termsig/k_scores
    k_termsig<<<dim3(136, 2, CH), dim3(256), 0, stream>>>(qkv, term, sig, c0);
    k_scores<<<dim3(136, 1, CH), dim3(256), 0, stream>>>(qkv, term, sig, scores, c0);
    k_softmax<<<dim3(NN / 4, CH), dim3(256), 0, stream>>>(scores);
    k_pv<<<dim3(NN / 64, 1, CH), dim3(256), 0, stream>>>(scores, vcT, attn, c0);
  }

  k_outproj<<<dim3(64, 8), dim3(256), 0, stream>>>(attn, wt + (size_t)6 * DIM * DIM, (float*)d_out);
}